// Round 2
// baseline (397.639 us; speedup 1.0000x reference)
//
#include <hip/hip_runtime.h>

// SpecEMA: y[b,c,t,f] = x[b,c,t,f] / sqrt(s[b,t,f]),
//   s_t = ALPHA*s_{t-1} + (1-ALPHA)*(x[b,0,t,f]^2 + x[b,1,t,f]^2), s_{-1}=state[f]
// Outputs: y [64,2,4000,96] then final_state [64,1,96], flat-concatenated.
//
// Three-phase chunked linear scan (chunk len L=20, K=200 chunks):
//   P1: per (chain, chunk) aggregate B_k  (s_in = 0)           [reads x once]
//   P2: per chain, serial scan over K chunk aggregates -> in-place prefixes
//   P3: per (chain, chunk) load prefix, scan + normalize + write [reads x, writes y]
// chain = (b, f-group-of-4): 64 * 24 = 1536 float4 chains.

namespace {
constexpr int Bdim = 64, Cdim = 2, Tdim = 4000, Fdim = 96;
constexpr int K = 200, L = 20;             // T = K * L
constexpr int FG = Fdim / 4;               // 24 float4 groups
constexpr int CHAINS = Bdim * FG;          // 1536
constexpr float kAlpha = 0.99f;
constexpr float kOneMinusAlpha = 0.01f;
constexpr float kAlphaL = 0.8179069376f;   // 0.99^20

typedef float v4f __attribute__((ext_vector_type(4)));

__device__ __forceinline__ v4f ld4(const float* p) {
  return *reinterpret_cast<const v4f*>(p);
}
__device__ __forceinline__ void st4(float* p, v4f v) {
  *reinterpret_cast<v4f*>(p) = v;
}
}  // namespace

// Phase 1: chunk-local EMA aggregate with s_in = 0, for chunks k in [0, K-1).
__global__ __launch_bounds__(256) void spec_ema_phase1(
    const float* __restrict__ x, float* __restrict__ bws) {
  const int g = blockIdx.x * 256 + threadIdx.x;   // [0, CHAINS*(K-1)), exact
  const int chain = g % CHAINS;
  const int k = g / CHAINS;
  const int b = chain / FG, fg = chain % FG;

  const size_t base =
      ((size_t)b * Cdim * Tdim + (size_t)k * L) * Fdim + (size_t)fg * 4;
  const float* p0 = x + base;                     // c = 0
  const float* p1 = p0 + (size_t)Tdim * Fdim;     // c = 1

  v4f s = 0.0f;
#pragma unroll 5
  for (int j = 0; j < L; ++j) {
    v4f x0 = ld4(p0 + (size_t)j * Fdim);
    v4f x1 = ld4(p1 + (size_t)j * Fdim);
    v4f abs2 = x0 * x0 + x1 * x1;
    s = s * kAlpha + abs2 * kOneMinusAlpha;
  }
  st4(bws + (size_t)g * 4, s);                    // bws[k][chain]
}

// Phase 2: per-chain serial scan over chunk aggregates; converts bws[k][chain]
// from "aggregate of chunk k" to "state entering chunk k" (in place).
__global__ __launch_bounds__(256) void spec_ema_phase2(
    const float* __restrict__ state, float* __restrict__ bws) {
  const int chain = blockIdx.x * 256 + threadIdx.x;  // [0, CHAINS), exact
  const int fg = chain % FG;

  v4f p = ld4(state + (size_t)fg * 4);            // state entering chunk 0
#pragma unroll 4
  for (int m = 0; m < K - 1; ++m) {
    float* slot = bws + ((size_t)m * CHAINS + chain) * 4;
    v4f bm = ld4(slot);                           // aggregate of chunk m
    st4(slot, p);                                 // overwrite with prefix
    p = p * kAlphaL + bm;
  }
  st4(bws + ((size_t)(K - 1) * CHAINS + chain) * 4, p);  // prefix of last chunk
}

// Phase 3: load prefix, scan + normalize + write.
__global__ __launch_bounds__(256) void spec_ema_phase3(
    const float* __restrict__ x, const float* __restrict__ bws,
    float* __restrict__ out) {
  const int g = blockIdx.x * 256 + threadIdx.x;   // [0, CHAINS*K), exact
  const int chain = g % CHAINS;
  const int k = g / CHAINS;
  const int b = chain / FG, fg = chain % FG;

  v4f s = ld4(bws + (size_t)g * 4);               // state entering chunk k

  const size_t base =
      ((size_t)b * Cdim * Tdim + (size_t)k * L) * Fdim + (size_t)fg * 4;
  const float* p0 = x + base;
  const float* p1 = p0 + (size_t)Tdim * Fdim;
  float* q0 = out + base;
  float* q1 = q0 + (size_t)Tdim * Fdim;

#pragma unroll 5
  for (int j = 0; j < L; ++j) {
    v4f x0 = ld4(p0 + (size_t)j * Fdim);
    v4f x1 = ld4(p1 + (size_t)j * Fdim);
    v4f abs2 = x0 * x0 + x1 * x1;
    s = s * kAlpha + abs2 * kOneMinusAlpha;
    v4f r;
    r.x = rsqrtf(s.x);
    r.y = rsqrtf(s.y);
    r.z = rsqrtf(s.z);
    r.w = rsqrtf(s.w);
    __builtin_nontemporal_store(x0 * r, reinterpret_cast<v4f*>(q0 + (size_t)j * Fdim));
    __builtin_nontemporal_store(x1 * r, reinterpret_cast<v4f*>(q1 + (size_t)j * Fdim));
  }

  if (k == K - 1) {
    st4(out + (size_t)Bdim * Cdim * Tdim * Fdim + (size_t)b * Fdim +
            (size_t)fg * 4,
        s);                                       // final_state [64,1,96]
  }
}

extern "C" void kernel_launch(void* const* d_in, const int* in_sizes, int n_in,
                              void* d_out, int out_size, void* d_ws, size_t ws_size,
                              hipStream_t stream) {
  const float* x = (const float*)d_in[0];      // [64, 2, 4000, 96] f32
  const float* state = (const float*)d_in[1];  // [1, 1, 96] f32
  float* out = (float*)d_out;
  float* bws = (float*)d_ws;                   // K*CHAINS*16 B ~= 4.9 MB

  spec_ema_phase1<<<CHAINS * (K - 1) / 256, 256, 0, stream>>>(x, bws);
  spec_ema_phase2<<<CHAINS / 256, 256, 0, stream>>>(state, bws);
  spec_ema_phase3<<<CHAINS * K / 256, 256, 0, stream>>>(x, bws, out);
}